// Round 1
// 2773.469 us; speedup vs baseline: 1.1517x; 1.1517x over previous
//
#include <hip/hip_runtime.h>
#include <cstdint>
#include <cstddef>

#define N_NODES 100000
#define M_EDGES 20000
#define P_PAIRS 1600000
#define CIN 768
#define HID 128
#define OUT_C 16
#define NLAYERS 16
#define LN_EPS 1e-5f

using half8  = __attribute__((ext_vector_type(8))) _Float16;
using half4v = __attribute__((ext_vector_type(4))) _Float16;
using half2v = __attribute__((ext_vector_type(2))) _Float16;
using f32x4  = __attribute__((ext_vector_type(4))) float;

#if defined(__has_builtin)
#if __has_builtin(__builtin_amdgcn_fdot2)
#define HAVE_FDOT2 1
#endif
#endif

// accumulate 8 halves (one quad-row segment) into 8 f32 accumulators, masked by m
__device__ __forceinline__ void acc8(float* acc, half8 v, _Float16 m) {
#ifdef HAVE_FDOT2
    half2v b0 = { m, (_Float16)0.f };
    half2v b1 = { (_Float16)0.f, m };
#pragma unroll
    for (int p = 0; p < 4; p++) {
        half2v h = { v[2 * p], v[2 * p + 1] };
        acc[2 * p]     = __builtin_amdgcn_fdot2(h, b0, acc[2 * p], false);
        acc[2 * p + 1] = __builtin_amdgcn_fdot2(h, b1, acc[2 * p + 1], false);
    }
#else
    float fm = (float)m;
#pragma unroll
    for (int p = 0; p < 8; p++) acc[p] += (float)v[p] * fm;
#endif
}

// ------------------------- CSR build -------------------------

__global__ void hist_kernel(const int* __restrict__ v_idx, const int* __restrict__ e_idx,
                            unsigned* __restrict__ cnt_v, unsigned* __restrict__ cnt_e) {
    int p = blockIdx.x * 256 + threadIdx.x;
    if (p < P_PAIRS) {
        atomicAdd(&cnt_v[v_idx[p]], 1u);
        atomicAdd(&cnt_e[e_idx[p]], 1u);
    }
}

// ---- parallel scan: 3 phases ----
#define SCAN_EPT 16
#define SCAN_CHUNK 4096   // 256 threads * 16

__global__ void scan_block_sums(const unsigned* __restrict__ cnt, int n,
                                unsigned* __restrict__ bsum) {
    __shared__ unsigned ws[4];
    int t = threadIdx.x;
    int base = blockIdx.x * SCAN_CHUNK + t * SCAN_EPT;
    unsigned s = 0;
#pragma unroll
    for (int i = 0; i < SCAN_EPT; i++) {
        int idx = base + i;
        if (idx < n) s += cnt[idx];
    }
#pragma unroll
    for (int off = 1; off < 64; off <<= 1) s += __shfl_xor(s, off);
    int lane = t & 63, w = t >> 6;
    if (lane == 0) ws[w] = s;
    __syncthreads();
    if (t == 0) bsum[blockIdx.x] = ws[0] + ws[1] + ws[2] + ws[3];
}

// single wave; B <= 64
__global__ void scan_tops(const unsigned* __restrict__ bsum, int B,
                          unsigned* __restrict__ bbase, unsigned* __restrict__ total_out) {
    int t = threadIdx.x;
    unsigned v = (t < B) ? bsum[t] : 0u;
    unsigned s = v;
#pragma unroll
    for (int off = 1; off < 64; off <<= 1) {
        unsigned u = __shfl_up(s, off);
        if (t >= off) s += u;
    }
    if (t < B) bbase[t] = s - v;
    if (t == 63) *total_out = s;
}

__global__ void scan_final(const unsigned* __restrict__ cnt, int n,
                           const unsigned* __restrict__ bbase,
                           unsigned* __restrict__ offs, unsigned* __restrict__ cur,
                           float* __restrict__ inv) {
    __shared__ unsigned wtot[4];
    int t = threadIdx.x;
    int lane = t & 63, w = t >> 6;
    int base = blockIdx.x * SCAN_CHUNK + t * SCAN_EPT;
    unsigned vals[SCAN_EPT];
    unsigned tsum = 0;
#pragma unroll
    for (int i = 0; i < SCAN_EPT; i++) {
        int idx = base + i;
        unsigned v = (idx < n) ? cnt[idx] : 0u;
        vals[i] = v;
        tsum += v;
    }
    unsigned s = tsum;
#pragma unroll
    for (int off = 1; off < 64; off <<= 1) {
        unsigned u = __shfl_up(s, off);
        if (lane >= off) s += u;
    }
    unsigned texcl = s - tsum;
    if (lane == 63) wtot[w] = s;
    __syncthreads();
    unsigned wbase = 0;
    for (int i = 0; i < w; i++) wbase += wtot[i];
    unsigned run = bbase[blockIdx.x] + wbase + texcl;
#pragma unroll
    for (int i = 0; i < SCAN_EPT; i++) {
        int idx = base + i;
        if (idx < n) {
            offs[idx] = run;
            cur[idx] = run;
            unsigned c = vals[i];
            inv[idx] = 1.0f / (float)(c > 1u ? c : 1u);
            run += c;
        }
    }
}

// ---- fills ----

__global__ void fill_v_kernel(const int* __restrict__ v_idx, const int* __restrict__ e_idx,
                              unsigned* __restrict__ cur_v, unsigned short* __restrict__ vert_nbr) {
    int p = blockIdx.x * 256 + threadIdx.x;
    if (p < P_PAIRS) {
        unsigned s = atomicAdd(&cur_v[v_idx[p]], 1u);
        vert_nbr[s] = (unsigned short)e_idx[p];   // e < 20000 fits u16
    }
}

__global__ void fill_e_kernel(const int* __restrict__ v_idx, const int* __restrict__ e_idx,
                              unsigned* __restrict__ cur_e, int* __restrict__ edge_nbr) {
    int p = blockIdx.x * 256 + threadIdx.x;
    if (p < P_PAIRS) {
        unsigned s = atomicAdd(&cur_e[e_idx[p]], 1u);
        edge_nbr[s] = v_idx[p];
    }
}

// ------------------------- weight transpose+convert -------------------------

__global__ void convert_wT_kernel(const float* __restrict__ W, _Float16* __restrict__ WT,
                                  int K) {
    const float* src = W + (size_t)blockIdx.y * K * 128;
    _Float16* dst = WT + (size_t)blockIdx.y * K * 128;
    int idx = blockIdx.x * 256 + threadIdx.x;
    if (idx < K * 128) {
        int k = idx >> 7, n = idx & 127;
        dst[(size_t)n * K + k] = (_Float16)src[idx];
    }
}

// ------------------------- MFMA GEMM -------------------------

#define BK  64
#define LDK 72

template<bool A_FP32, bool OUT_HALF>
__global__ __launch_bounds__(256) void mfma_gemm_kernel(
    const void* __restrict__ Ap, const _Float16* __restrict__ Bt,
    const float* __restrict__ bias, void* __restrict__ outp,
    int nrows, int K) {
    __shared__ _Float16 Asm[128 * LDK];
    __shared__ _Float16 Bsm[128 * LDK];
    int tid = threadIdx.x;
    int row0 = blockIdx.x * 128;
    int lane = tid & 63, wave = tid >> 6;
    int wy = wave >> 1, wx = wave & 1;
    int m16 = lane & 15, quad = lane >> 4;

    f32x4 acc[4][4];
#pragma unroll
    for (int r = 0; r < 4; r++)
#pragma unroll
        for (int c = 0; c < 4; c++) acc[r][c] = (f32x4)0.f;

    float bv[4];
#pragma unroll
    for (int c = 0; c < 4; c++) bv[c] = bias[wx * 64 + c * 16 + m16];

    for (int k0 = 0; k0 < K; k0 += BK) {
        __syncthreads();
        if (A_FP32) {
            const float* A = (const float*)Ap;
#pragma unroll
            for (int i = 0; i < 8; i++) {
                int idx = tid + i * 256;
                int r = idx >> 4, c = idx & 15;
                int rg = row0 + r; if (rg >= nrows) rg = nrows - 1;
                float4 v = *(const float4*)(A + (size_t)rg * K + k0 + c * 4);
                half4v h = { (_Float16)v.x, (_Float16)v.y, (_Float16)v.z, (_Float16)v.w };
                *(half4v*)&Asm[r * LDK + c * 4] = h;
            }
        } else {
            const _Float16* A = (const _Float16*)Ap;
#pragma unroll
            for (int i = 0; i < 4; i++) {
                int idx = tid + i * 256;
                int r = idx >> 3, c = idx & 7;
                int rg = row0 + r; if (rg >= nrows) rg = nrows - 1;
                half8 v = *(const half8*)(A + (size_t)rg * K + k0 + c * 8);
                *(half8*)&Asm[r * LDK + c * 8] = v;
            }
        }
#pragma unroll
        for (int i = 0; i < 4; i++) {
            int idx = tid + i * 256;
            int r = idx >> 3, c = idx & 7;
            half8 v = *(const half8*)(Bt + (size_t)r * K + k0 + c * 8);
            *(half8*)&Bsm[r * LDK + c * 8] = v;
        }
        __syncthreads();
#pragma unroll
        for (int ks = 0; ks < 2; ks++) {
            half8 af[4], bf[4];
#pragma unroll
            for (int r = 0; r < 4; r++)
                af[r] = *(half8*)&Asm[(wy * 64 + r * 16 + m16) * LDK + ks * 32 + quad * 8];
#pragma unroll
            for (int c = 0; c < 4; c++)
                bf[c] = *(half8*)&Bsm[(wx * 64 + c * 16 + m16) * LDK + ks * 32 + quad * 8];
#pragma unroll
            for (int r = 0; r < 4; r++)
#pragma unroll
                for (int c = 0; c < 4; c++)
                    acc[r][c] = __builtin_amdgcn_mfma_f32_16x16x32_f16(af[r], bf[c], acc[r][c], 0, 0, 0);
        }
    }
#pragma unroll
    for (int r = 0; r < 4; r++) {
#pragma unroll
        for (int v = 0; v < 4; v++) {
            int m = wy * 64 + r * 16 + quad * 4 + v;
            int row = row0 + m;
            if (row < nrows) {
#pragma unroll
                for (int c = 0; c < 4; c++) {
                    int n = wx * 64 + c * 16 + m16;
                    float val = acc[r][c][v] + bv[c];
                    if (OUT_HALF) ((_Float16*)outp)[(size_t)row * HID + n] = (_Float16)val;
                    else          ((float*)outp)[(size_t)row * HID + n] = val;
                }
            }
        }
    }
}

// ------------------------- LayerNorm + ReLU (layer 0 only) -------------------------

__global__ __launch_bounds__(256) void ln_relu_kernel(const float* __restrict__ x,
                                                      const float* __restrict__ g,
                                                      const float* __restrict__ b,
                                                      _Float16* __restrict__ a) {
    int row = (blockIdx.x * 256 + threadIdx.x) >> 6;
    int lane = threadIdx.x & 63;
    if (row >= N_NODES) return;
    float2 v = *(const float2*)(x + (size_t)row * HID + 2 * lane);
    float s = v.x + v.y;
#pragma unroll
    for (int off = 1; off < 64; off <<= 1) s += __shfl_xor(s, off);
    float mu = s * (1.0f / 128.0f);
    float d0 = v.x - mu, d1 = v.y - mu;
    float q = d0 * d0 + d1 * d1;
#pragma unroll
    for (int off = 1; off < 64; off <<= 1) q += __shfl_xor(q, off);
    float rstd = rsqrtf(q * (1.0f / 128.0f) + LN_EPS);
    float2 gg = *(const float2*)(g + 2 * lane);
    float2 bb = *(const float2*)(b + 2 * lane);
    float h0 = fmaxf(d0 * rstd * gg.x + bb.x, 0.f);
    float h1 = fmaxf(d1 * rstd * gg.y + bb.y, 0.f);
    half2v h = { (_Float16)h0, (_Float16)h1 };
    *(half2v*)(a + (size_t)row * HID + 2 * lane) = h;
}

// ------------------------- edge aggregation: quad-row gather, one wave per edge -------------------------

__global__ __launch_bounds__(256) void edge_agg_kernel(const _Float16* __restrict__ a,
                                                       const int* __restrict__ edge_nbr,
                                                       const unsigned* __restrict__ offs,
                                                       const float* __restrict__ inv_ce,
                                                       _Float16* __restrict__ Ae) {
    int m = blockIdx.x * 4 + (threadIdx.x >> 6);
    int lane = threadIdx.x & 63;
    int g = lane >> 4, t = lane & 15;      // 4 groups of 16 lanes; group gathers one row (16B/lane)
    unsigned beg = offs[m], end = offs[m + 1];
    float acc[8] = {0.f, 0.f, 0.f, 0.f, 0.f, 0.f, 0.f, 0.f};
    const _Float16* base = a + t * 8;
    unsigned j = beg;
    // 16 rows per iteration: 4 independent 1KB gathers in flight
    for (; j + 16 <= end; j += 16) {
        int v0 = edge_nbr[j + g];
        int v1 = edge_nbr[j + 4 + g];
        int v2 = edge_nbr[j + 8 + g];
        int v3 = edge_nbr[j + 12 + g];
        half8 h0 = *(const half8*)(base + (size_t)v0 * HID);
        half8 h1 = *(const half8*)(base + (size_t)v1 * HID);
        half8 h2 = *(const half8*)(base + (size_t)v2 * HID);
        half8 h3 = *(const half8*)(base + (size_t)v3 * HID);
        acc8(acc, h0, (_Float16)1.f);
        acc8(acc, h1, (_Float16)1.f);
        acc8(acc, h2, (_Float16)1.f);
        acc8(acc, h3, (_Float16)1.f);
    }
    // 8-row mid step
    if (j + 8 <= end) {
        int v0 = edge_nbr[j + g];
        int v1 = edge_nbr[j + 4 + g];
        half8 h0 = *(const half8*)(base + (size_t)v0 * HID);
        half8 h1 = *(const half8*)(base + (size_t)v1 * HID);
        acc8(acc, h0, (_Float16)1.f);
        acc8(acc, h1, (_Float16)1.f);
        j += 8;
    }
    // masked tail quads
    for (; j < end; j += 4) {
        unsigned idx = j + g;
        bool val = idx < end;
        int v = edge_nbr[val ? idx : beg];
        half8 h = *(const half8*)(base + (size_t)v * HID);
        acc8(acc, h, val ? (_Float16)1.f : (_Float16)0.f);
    }
    // reduce across the 4 groups
#pragma unroll
    for (int i = 0; i < 8; i++) {
        acc[i] += __shfl_xor(acc[i], 16);
        acc[i] += __shfl_xor(acc[i], 32);
    }
    if (lane < 16) {
        float ic = inv_ce[m];
        half8 o;
#pragma unroll
        for (int i = 0; i < 8; i++) o[i] = (_Float16)(acc[i] * ic);
        *(half8*)(Ae + (size_t)m * HID + t * 8) = o;
    }
}

// ------------------------- vertex aggregation + residual + fused next-layer LN -------------------------

__global__ __launch_bounds__(256) void vert_fused_kernel(
    const _Float16* __restrict__ Xe, const unsigned short* __restrict__ vert_nbr,
    const unsigned* __restrict__ offs, const float* __restrict__ inv_cv,
    float* __restrict__ x, const float* __restrict__ gw, const float* __restrict__ bw,
    _Float16* __restrict__ a, int do_ln) {
    int v = blockIdx.x * 4 + (threadIdx.x >> 6);
    int lane = threadIdx.x & 63;
    int g = lane >> 4, t = lane & 15;
    unsigned beg = offs[v], end = offs[v + 1];
    float acc[8] = {0.f, 0.f, 0.f, 0.f, 0.f, 0.f, 0.f, 0.f};
    const _Float16* base = Xe + t * 8;
    unsigned j = beg;
    for (; j + 16 <= end; j += 16) {
        int e0 = vert_nbr[j + g];
        int e1 = vert_nbr[j + 4 + g];
        int e2 = vert_nbr[j + 8 + g];
        int e3 = vert_nbr[j + 12 + g];
        half8 h0 = *(const half8*)(base + (size_t)e0 * HID);
        half8 h1 = *(const half8*)(base + (size_t)e1 * HID);
        half8 h2 = *(const half8*)(base + (size_t)e2 * HID);
        half8 h3 = *(const half8*)(base + (size_t)e3 * HID);
        acc8(acc, h0, (_Float16)1.f);
        acc8(acc, h1, (_Float16)1.f);
        acc8(acc, h2, (_Float16)1.f);
        acc8(acc, h3, (_Float16)1.f);
    }
    if (j + 8 <= end) {
        int e0 = vert_nbr[j + g];
        int e1 = vert_nbr[j + 4 + g];
        half8 h0 = *(const half8*)(base + (size_t)e0 * HID);
        half8 h1 = *(const half8*)(base + (size_t)e1 * HID);
        acc8(acc, h0, (_Float16)1.f);
        acc8(acc, h1, (_Float16)1.f);
        j += 8;
    }
    for (; j < end; j += 4) {
        unsigned idx = j + g;
        bool val = idx < end;
        int e = vert_nbr[val ? idx : beg];
        half8 h = *(const half8*)(base + (size_t)e * HID);
        acc8(acc, h, val ? (_Float16)1.f : (_Float16)0.f);
    }
#pragma unroll
    for (int i = 0; i < 8; i++) {
        acc[i] += __shfl_xor(acc[i], 16);
        acc[i] += __shfl_xor(acc[i], 32);
    }
    if (lane < 16) {
        float ic = inv_cv[v];
        float xv[8];
        float4* xp = (float4*)(x + (size_t)v * HID + t * 8);
        float4 x0 = xp[0], x1 = xp[1];
        xv[0] = x0.x; xv[1] = x0.y; xv[2] = x0.z; xv[3] = x0.w;
        xv[4] = x1.x; xv[5] = x1.y; xv[6] = x1.z; xv[7] = x1.w;
#pragma unroll
        for (int i = 0; i < 8; i++) xv[i] += fmaxf(acc[i] * ic, 0.f);
        x0.x = xv[0]; x0.y = xv[1]; x0.z = xv[2]; x0.w = xv[3];
        x1.x = xv[4]; x1.y = xv[5]; x1.z = xv[6]; x1.w = xv[7];
        xp[0] = x0; xp[1] = x1;
        if (do_ln) {
            float s = 0.f;
#pragma unroll
            for (int i = 0; i < 8; i++) s += xv[i];
#pragma unroll
            for (int off = 1; off < 16; off <<= 1) s += __shfl_xor(s, off);
            float mu = s * (1.0f / 128.0f);
            float d[8];
            float q = 0.f;
#pragma unroll
            for (int i = 0; i < 8; i++) { d[i] = xv[i] - mu; q += d[i] * d[i]; }
#pragma unroll
            for (int off = 1; off < 16; off <<= 1) q += __shfl_xor(q, off);
            float rstd = rsqrtf(q * (1.0f / 128.0f) + LN_EPS);
            float4 g0 = *(const float4*)(gw + t * 8);
            float4 g1 = *(const float4*)(gw + t * 8 + 4);
            float4 b0 = *(const float4*)(bw + t * 8);
            float4 b1 = *(const float4*)(bw + t * 8 + 4);
            float gg[8] = {g0.x, g0.y, g0.z, g0.w, g1.x, g1.y, g1.z, g1.w};
            float bb[8] = {b0.x, b0.y, b0.z, b0.w, b1.x, b1.y, b1.z, b1.w};
            half8 o;
#pragma unroll
            for (int i = 0; i < 8; i++)
                o[i] = (_Float16)fmaxf(d[i] * rstd * gg[i] + bb[i], 0.f);
            *(half8*)(a + (size_t)v * HID + t * 8) = o;
        }
    }
}

// ------------------------- head: x @ W_out + b_out, log_softmax -------------------------

__global__ __launch_bounds__(256) void out_kernel(const float* __restrict__ x,
                                                  const float* __restrict__ Wo,
                                                  const float* __restrict__ bo,
                                                  float* __restrict__ out) {
    __shared__ float Ws[128][16];
    __shared__ float rowbuf[16][132];
    __shared__ float bsm[16];
    int tid = threadIdx.x;
#pragma unroll
    for (int i = 0; i < 8; i++) {
        int idx = tid + i * 256;
        ((float*)Ws)[idx] = Wo[idx];
    }
    if (tid < 16) bsm[tid] = bo[tid];
    int row0 = blockIdx.x * 16;
    int w = tid >> 6, lane = tid & 63;
#pragma unroll
    for (int i = 0; i < 8; i++) {
        int idx = lane + i * 64;
        int r = idx >> 7, k = idx & 127;
        int row = row0 + w * 4 + r;
        rowbuf[w * 4 + r][k] = (row < N_NODES) ? x[(size_t)row * HID + k] : 0.f;
    }
    __syncthreads();
    int r = lane >> 4, c = lane & 15;
    int row = row0 + w * 4 + r;
    float acc = bsm[c];
#pragma unroll
    for (int k = 0; k < 128; k++) acc += rowbuf[w * 4 + r][k] * Ws[k][c];
    float mx = acc;
#pragma unroll
    for (int off = 1; off < 16; off <<= 1) mx = fmaxf(mx, __shfl_xor(mx, off));
    float e = expf(acc - mx);
    float s = e;
#pragma unroll
    for (int off = 1; off < 16; off <<= 1) s += __shfl_xor(s, off);
    float val = acc - mx - logf(s);
    if (row < N_NODES) out[(size_t)row * OUT_C + c] = val;
}

// ------------------------- launch -------------------------

extern "C" void kernel_launch(void* const* d_in, const int* in_sizes, int n_in,
                              void* d_out, int out_size, void* d_ws, size_t ws_size,
                              hipStream_t stream) {
    const float* X     = (const float*)d_in[0];
    const int*   v_idx = (const int*)d_in[1];
    const int*   e_idx = (const int*)d_in[2];
    const float* W_enc = (const float*)d_in[3];
    const float* b_enc = (const float*)d_in[4];
    const float* ln_g  = (const float*)d_in[5];
    const float* ln_b  = (const float*)d_in[6];
    const float* Wt    = (const float*)d_in[7];
    const float* bt    = (const float*)d_in[8];
    const float* W_out = (const float*)d_in[9];
    const float* b_out = (const float*)d_in[10];
    float* out = (float*)d_out;

    char* ws = (char*)d_ws;
    auto alloc = [&](size_t bytes) -> void* {
        void* p = (void*)ws;
        ws += (bytes + 255) & ~(size_t)255;
        return p;
    };
    float*    x       = (float*)alloc((size_t)N_NODES * HID * 4);
    _Float16* a_h     = (_Float16*)alloc((size_t)N_NODES * HID * 2);
    _Float16* Ae_h    = (_Float16*)alloc((size_t)M_EDGES * HID * 2);
    _Float16* Xe_h    = (_Float16*)alloc((size_t)M_EDGES * HID * 2);
    _Float16* WencT_h = (_Float16*)alloc((size_t)CIN * HID * 2);
    _Float16* WtT_h   = (_Float16*)alloc((size_t)NLAYERS * HID * HID * 2);
    int* edge_nbr = (int*)alloc((size_t)P_PAIRS * 4);
    unsigned short* vert_nbr = (unsigned short*)alloc((size_t)P_PAIRS * 2);
    unsigned* cnt_e = (unsigned*)alloc((size_t)(M_EDGES + N_NODES) * 4);
    unsigned* cnt_v = cnt_e + M_EDGES;
    unsigned* offs_e = (unsigned*)alloc((size_t)(M_EDGES + 1) * 4);
    unsigned* offs_v = (unsigned*)alloc((size_t)(N_NODES + 1) * 4);
    unsigned* cur_e  = (unsigned*)alloc((size_t)M_EDGES * 4);
    unsigned* cur_v  = (unsigned*)alloc((size_t)N_NODES * 4);
    float* inv_ce = (float*)alloc((size_t)M_EDGES * 4);
    float* inv_cv = (float*)alloc((size_t)N_NODES * 4);
    unsigned* bsum_e = (unsigned*)alloc(64 * 4);
    unsigned* bbase_e = (unsigned*)alloc(64 * 4);
    unsigned* bsum_v = (unsigned*)alloc(64 * 4);
    unsigned* bbase_v = (unsigned*)alloc(64 * 4);

    const int BE = (M_EDGES + SCAN_CHUNK - 1) / SCAN_CHUNK;   // 5
    const int BV = (N_NODES + SCAN_CHUNK - 1) / SCAN_CHUNK;   // 25

    // CSR build
    hipMemsetAsync(cnt_e, 0, (size_t)(M_EDGES + N_NODES) * 4, stream);
    hist_kernel<<<(P_PAIRS + 255) / 256, 256, 0, stream>>>(v_idx, e_idx, cnt_v, cnt_e);
    scan_block_sums<<<BE, 256, 0, stream>>>(cnt_e, M_EDGES, bsum_e);
    scan_tops<<<1, 64, 0, stream>>>(bsum_e, BE, bbase_e, offs_e + M_EDGES);
    scan_final<<<BE, 256, 0, stream>>>(cnt_e, M_EDGES, bbase_e, offs_e, cur_e, inv_ce);
    scan_block_sums<<<BV, 256, 0, stream>>>(cnt_v, N_NODES, bsum_v);
    scan_tops<<<1, 64, 0, stream>>>(bsum_v, BV, bbase_v, offs_v + N_NODES);
    scan_final<<<BV, 256, 0, stream>>>(cnt_v, N_NODES, bbase_v, offs_v, cur_v, inv_cv);
    fill_v_kernel<<<(P_PAIRS + 255) / 256, 256, 0, stream>>>(v_idx, e_idx, cur_v, vert_nbr);
    fill_e_kernel<<<(P_PAIRS + 255) / 256, 256, 0, stream>>>(v_idx, e_idx, cur_e, edge_nbr);

    // weight conversion
    {
        dim3 g1((CIN * HID + 255) / 256, 1);
        convert_wT_kernel<<<g1, 256, 0, stream>>>(W_enc, WencT_h, CIN);
        dim3 g2((HID * HID + 255) / 256, NLAYERS);
        convert_wT_kernel<<<g2, 256, 0, stream>>>(Wt, WtT_h, HID);
    }

    // encoder: x = X @ W_enc + b_enc
    mfma_gemm_kernel<true, false><<<(N_NODES + 127) / 128, 256, 0, stream>>>(
        (const void*)X, WencT_h, b_enc, (void*)x, N_NODES, CIN);

    // layer-0 LN
    ln_relu_kernel<<<(N_NODES * 64 + 255) / 256, 256, 0, stream>>>(
        x, ln_g, ln_b, a_h);

    // 16 layers
    for (int l = 0; l < NLAYERS; l++) {
        edge_agg_kernel<<<M_EDGES / 4, 256, 0, stream>>>(a_h, edge_nbr, offs_e, inv_ce, Ae_h);
        mfma_gemm_kernel<false, true><<<(M_EDGES + 127) / 128, 256, 0, stream>>>(
            (const void*)Ae_h, WtT_h + (size_t)l * HID * HID, bt + l * HID,
            (void*)Xe_h, M_EDGES, HID);
        int lnext = (l + 1 < NLAYERS) ? (l + 1) : (NLAYERS - 1);  // pointer kept valid; unused when do_ln=0
        vert_fused_kernel<<<N_NODES / 4, 256, 0, stream>>>(
            Xe_h, vert_nbr, offs_v, inv_cv, x,
            ln_g + (size_t)lnext * HID, ln_b + (size_t)lnext * HID, a_h,
            (l + 1 < NLAYERS) ? 1 : 0);
    }

    // head
    out_kernel<<<(N_NODES + 15) / 16, 256, 0, stream>>>(x, W_out, b_out, out);
}